// Round 11
// baseline (1467.596 us; speedup 1.0000x reference)
//
#include <hip/hip_runtime.h>
#include <math.h>
#include <stdint.h>

#define N_TOK 16384
#define DIM   1024
#define NEXP  8
#define HID   2048
#define OUTD  1024
#define PADTOT 34816   // 2*N_TOK + 8*256 : padded compacted-row upper bound (136 tiles of 256)

typedef __attribute__((ext_vector_type(8))) short short8;
typedef __attribute__((ext_vector_type(8))) _Float16 f16x8;
typedef __attribute__((ext_vector_type(4))) float f32x4;
typedef __attribute__((ext_vector_type(4))) unsigned short u16x4;

__device__ __forceinline__ unsigned short f2h(float f) {
  return __builtin_bit_cast(unsigned short, (_Float16)f);   // RNE
}
__device__ __forceinline__ float h2f(unsigned short h) {
  return (float)__builtin_bit_cast(_Float16, h);
}
__device__ __forceinline__ float gelu_exact(float a) {
  return 0.5f * a * (1.0f + erff(a * 0.70710678118654752f));
}

// ---------------- gate: fp64 math, high-TLP, NO global atomics ----------------
__global__ __launch_bounds__(256) void gate_kernel(
    const float* __restrict__ x, const float* __restrict__ Wg1,
    const float* __restrict__ Wg2,
    int* __restrict__ tok_e, float* __restrict__ tok_w)
{
  const int tid = threadIdx.x;
  const int lane = tid & 63, wid = tid >> 6;
  const f32x4* __restrict__ Wg1v = (const f32x4*)Wg1;   // [1024][4xf32x4]
  f32x4 wreg[4][4];
#pragma unroll
  for (int i = 0; i < 4; ++i)
#pragma unroll
    for (int c = 0; c < 4; ++c)
      wreg[i][c] = Wg1v[(size_t)(tid + 256 * i) * 4 + c];

  __shared__ double red[4 * 16];

  for (int tk = 0; tk < 8; ++tk) {
    const int n = blockIdx.x * 8 + tk;
    double xv[4];
#pragma unroll
    for (int i = 0; i < 4; ++i)
      xv[i] = (double)x[(size_t)n * DIM + tid + 256 * i];
    double acc[16];
#pragma unroll
    for (int j = 0; j < 16; ++j) acc[j] = 0.0;
#pragma unroll
    for (int i = 0; i < 4; ++i)
#pragma unroll
      for (int c = 0; c < 4; ++c)
#pragma unroll
        for (int q = 0; q < 4; ++q)
          acc[c * 4 + q] += xv[i] * (double)wreg[i][c][q];
#pragma unroll
    for (int j = 0; j < 16; ++j)
#pragma unroll
      for (int s = 32; s > 0; s >>= 1) acc[j] += __shfl_xor(acc[j], s);
    if (lane == 0) {
#pragma unroll
      for (int j = 0; j < 16; ++j) red[wid * 16 + j] = acc[j];
    }
    __syncthreads();
    if (wid == 0) {
      double t = 0.0;
      if (lane < 16) {
        t = red[lane] + red[16 + lane] + red[32 + lane] + red[48 + lane];
        t = tanh(t);
      }
      const int e = lane & 7;
      double ge = 0.0;
#pragma unroll
      for (int j = 0; j < 16; ++j) {
        double tj = __shfl(t, j);
        ge += tj * (double)Wg2[j * 8 + e];
      }
      double m = ge;
#pragma unroll
      for (int s = 1; s < 8; s <<= 1) m = fmax(m, __shfl_xor(m, s));
      double p = exp(ge - m);
      double ssum = p;
#pragma unroll
      for (int s = 1; s < 8; s <<= 1) ssum += __shfl_xor(ssum, s);
      double wsm = p / ssum;
      unsigned long long key =
          (((unsigned long long)__double_as_longlong(wsm)) & ~7ULL) |
          (unsigned long long)(7 - e);
      unsigned long long k1 = key;
#pragma unroll
      for (int s = 1; s < 8; s <<= 1) { unsigned long long o = __shfl_xor(k1, s); k1 = (o > k1) ? o : k1; }
      int e1 = 7 - (int)(k1 & 7ULL);
      unsigned long long k2 = (e == e1) ? 0ULL : key;
#pragma unroll
      for (int s = 1; s < 8; s <<= 1) { unsigned long long o = __shfl_xor(k2, s); k2 = (o > k2) ? o : k2; }
      int e2 = 7 - (int)(k2 & 7ULL);
      double w1v = __longlong_as_double((long long)(k1 & ~7ULL));
      double w2v = __longlong_as_double((long long)(k2 & ~7ULL));
      double inv = 1.0 / (w1v + w2v + 1e-12);
      if (lane == 0) {
        tok_e[2 * n] = e1; tok_e[2 * n + 1] = e2;
        tok_w[2 * n] = (float)(w1v * inv); tok_w[2 * n + 1] = (float)(w2v * inv);
      }
    }
    __syncthreads();
  }
}

// ---------------- hist: LDS histogram, 8 global atomics per block ------------
__global__ __launch_bounds__(256) void hist_kernel(
    const int* __restrict__ tok_e, int* __restrict__ cnt)
{
  __shared__ int h[NEXP];
  const int tid = threadIdx.x;
  if (tid < NEXP) h[tid] = 0;
  __syncthreads();
  const int base = blockIdx.x * 512;
  atomicAdd(&h[tok_e[base + tid]], 1);
  atomicAdd(&h[tok_e[base + 256 + tid]], 1);
  __syncthreads();
  if (tid < NEXP) atomicAdd(&cnt[tid], h[tid]);
}

// offsets padded to multiples of 256 so every 256-row tile is single-expert
__global__ void offsets_kernel(const int* __restrict__ cnt, int* __restrict__ off,
                               int* __restrict__ cur) {
  if (threadIdx.x == 0) {
    int a = 0;
    for (int e = 0; e < NEXP; ++e) {
      off[e] = a; cur[e] = a;
      a += (cnt[e] + 255) & ~255;
    }
    off[NEXP] = a;
  }
}

// ---------------- scatter: per-block LDS rank + one base-claim per expert ----
__global__ __launch_bounds__(256) void scatter_kernel(
    const int* __restrict__ tok_e, const float* __restrict__ tok_w,
    int* __restrict__ cur, int* __restrict__ rows, float* __restrict__ roww,
    int* __restrict__ pair)
{
  __shared__ int lcnt[NEXP];
  __shared__ int lbase[NEXP];
  const int tid = threadIdx.x;
  if (tid < NEXP) lcnt[tid] = 0;
  __syncthreads();
  const int n = blockIdx.x * 256 + tid;
  const int e0 = tok_e[2 * n], e1 = tok_e[2 * n + 1];
  const int r0 = atomicAdd(&lcnt[e0], 1);
  const int r1 = atomicAdd(&lcnt[e1], 1);
  __syncthreads();
  if (tid < NEXP) lbase[tid] = atomicAdd(&cur[tid], lcnt[tid]);
  __syncthreads();
  const int p0 = lbase[e0] + r0;
  const int p1 = lbase[e1] + r1;
  rows[p0] = n; roww[p0] = tok_w[2 * n];     pair[2 * n]     = p0;
  rows[p1] = n; roww[p1] = tok_w[2 * n + 1]; pair[2 * n + 1] = p1;
}

// ---------------- fp32 -> fp16 converts ----------------
__global__ __launch_bounds__(256) void convert_x_kernel(
    const float* __restrict__ x, unsigned short* __restrict__ xh)
{
  size_t i = ((size_t)blockIdx.x * 256 + threadIdx.x) * 8;
  f32x4 a = *(const f32x4*)(x + i);
  f32x4 b = *(const f32x4*)(x + i + 4);
  short8 o;
#pragma unroll
  for (int q = 0; q < 4; ++q) { o[q] = (short)f2h(a[q]); o[q + 4] = (short)f2h(b[q]); }
  *(short8*)(xh + i) = o;
}

// transpose+convert: W[e][K][N] fp32 -> Wt[e][N][K] fp16
__global__ __launch_bounds__(256) void wconv_kernel(
    const float* __restrict__ W, unsigned short* __restrict__ Wt,
    const int K, const int N)
{
  __shared__ float t[32][33];
  const int e = blockIdx.z;
  const float* We = W + (size_t)e * K * N;
  unsigned short* Wte = Wt + (size_t)e * K * N;
  const int n0 = blockIdx.x * 32, k0 = blockIdx.y * 32;
  const int tid = threadIdx.x;
  const int r = tid >> 3, c4 = (tid & 7) * 4;
  f32x4 v = *(const f32x4*)(We + (size_t)(k0 + r) * N + n0 + c4);
  t[r][c4 + 0] = v[0]; t[r][c4 + 1] = v[1]; t[r][c4 + 2] = v[2]; t[r][c4 + 3] = v[3];
  __syncthreads();
  u16x4 o;
#pragma unroll
  for (int q = 0; q < 4; ++q) o[q] = f2h(t[c4 + q][r]);
  *(u16x4*)(Wte + (size_t)(n0 + r) * K + k0 + c4) = o;
}

// ============ 256x256 8-wave routed GEMM, 4-phase/K-tile (m201-style) ============
// Phases: q00 -> q01 -> q11 -> q10; 24 ds_read_b128/tile (frags held across phases);
// quarter-stage stream [SB1(t+1)@P0, SA1(t+1)@P1, SB0(t+2)@P2, SA0(t+2)@P3];
// uniform counted vmcnt(8) at P0/P1/P3 ends, bare barrier at P2 end.
// MODE 0: A = gathered xh rows; MODE 1: A = act2; MODE 2: atomic fallback; MODE 3: Y out.

#define SA_Q(SB_, QM_, T_) do {                                               \
  _Pragma("unroll") for (int i_ = 0; i_ < 2; ++i_)                            \
    __builtin_amdgcn_global_load_lds(                                         \
      (const __attribute__((address_space(1))) void*)(Abase + aoff[QM_][i_] + (size_t)(T_)*64 + kc8), \
      (__attribute__((address_space(3))) void*)(lds + (SB_)*16384 + (QM_)*4096 + i_*8192 + tid*8), \
      16, 0, 0);                                                              \
} while (0)

#define SB_Q(SB_, QN_, T_) do {                                               \
  _Pragma("unroll") for (int i_ = 0; i_ < 2; ++i_)                            \
    __builtin_amdgcn_global_load_lds(                                         \
      (const __attribute__((address_space(1))) void*)(Bbase + boff[QN_][i_] + (size_t)(T_)*64 + kc8), \
      (__attribute__((address_space(3))) void*)(lds + 32768 + (SB_)*16384 + (QN_)*2048 + (i_*2 + (tid >> 8))*4096 + (tid & 255)*8), \
      16, 0, 0);                                                              \
} while (0)

// 8 reads into DST_[4][2]: the QM_ 64-row half of this wave's 128 rows
#define LOAD_AFH(DST_, QM_) do {                                              \
    _Pragma("unroll") for (int mi = 0; mi < 4; ++mi)                          \
    _Pragma("unroll") for (int kk = 0; kk < 2; ++kk) {                        \
      const int row_ = wm*128 + (QM_)*64 + mi*16 + l15;                       \
      const int ch_ = ((kk*4 + lh) ^ (row_ & 7));                             \
      DST_[mi][kk] = *(const short8*)(ldsAb + row_*64 + ch_*8);               \
    }                                                                         \
} while (0)

// 4 reads into DST_[2][2]: the QN_ 32-col half of this wave's 64 cols
#define LOAD_BFH(DST_, QN_) do {                                              \
    _Pragma("unroll") for (int ni = 0; ni < 2; ++ni)                          \
    _Pragma("unroll") for (int kk = 0; kk < 2; ++kk) {                        \
      const int row_ = wn*64 + (QN_)*32 + ni*16 + l15;                        \
      const int ch_ = ((kk*4 + lh) ^ (row_ & 7));                             \
      DST_[ni][kk] = *(const short8*)(ldsBb + row_*64 + ch_*8);               \
    }                                                                         \
} while (0)

// 16 MFMA for quadrant (QM_,QN_) using held fragments
#define MFMA_Q(QM_, QN_, AF_, BF_) do {                                       \
    __builtin_amdgcn_s_setprio(1);                                            \
    _Pragma("unroll") for (int kk = 0; kk < 2; ++kk)                          \
    _Pragma("unroll") for (int mi = 0; mi < 4; ++mi)                          \
    _Pragma("unroll") for (int ni = 0; ni < 2; ++ni)                          \
      acc[(QM_)*4 + mi][(QN_)*2 + ni] = __builtin_amdgcn_mfma_f32_16x16x32_f16( \
          __builtin_bit_cast(f16x8, BF_[ni][kk]),                             \
          __builtin_bit_cast(f16x8, AF_[mi][kk]),                             \
          acc[(QM_)*4 + mi][(QN_)*2 + ni], 0, 0, 0);                          \
    __builtin_amdgcn_s_setprio(0);                                            \
} while (0)

#define BARRIER() asm volatile("s_barrier" ::: "memory")
#define PH_END(N_) do {                                                       \
  asm volatile("s_waitcnt vmcnt(" #N_ ") lgkmcnt(0)" ::: "memory");           \
  asm volatile("s_barrier" ::: "memory");                                     \
} while (0)

template<int MODE>
__global__ __launch_bounds__(512, 1) void gemm256_kernel(
    const unsigned short* __restrict__ Abase,
    const unsigned short* __restrict__ Bbase,
    unsigned short* __restrict__ Oh,
    float* __restrict__ Of,
    const float* __restrict__ bias,
    const int* __restrict__ rows,
    const float* __restrict__ roww,
    const int* __restrict__ off,
    const int K, const int N, const int Astride, const int c0, const int lgGX)
{
  // XCD-chunked bijective block remap (m204)
  const unsigned orig = blockIdx.x, nwg = gridDim.x;
  const unsigned q8 = nwg >> 3, r8 = nwg & 7;
  const unsigned xcd = orig & 7, pos = orig >> 3;
  const unsigned wrk = (xcd < r8 ? xcd * (q8 + 1) : r8 * (q8 + 1) + (xcd - r8) * q8) + pos;
  const int tn = (int)(wrk & ((1u << lgGX) - 1u));
  const int rowbase = c0 + (int)(wrk >> lgGX) * 256;

  const int off8 = off[NEXP];
  if (rowbase >= off8) return;
  int e = 0;
  while (e < NEXP - 1 && rowbase >= off[e + 1]) ++e;

  // LDS: A[2 buf][256][64] fp16 @0, B[2 buf][256][64] fp16 @32768 shorts = 128 KiB
  __shared__ __align__(16) unsigned short lds[65536];

  const int tid = threadIdx.x, lane = tid & 63, wid = tid >> 6;
  const int wm = wid >> 2, wn = wid & 3;       // 2 x 4 waves, each owns 128x64
  const int l15 = lane & 15, lh = lane >> 4;
  const int kc8 = ((tid & 7) ^ ((tid >> 3) & 7)) * 8;   // pre-swizzled source chunk

  f32x4 acc[8][4] = {};

  // per-thread staging offsets (element units)
  size_t aoff[2][2];
#pragma unroll
  for (int qm = 0; qm < 2; ++qm)
#pragma unroll
    for (int i = 0; i < 2; ++i) {
      int grow = rowbase + i * 128 + qm * 64 + (tid >> 3);
      size_t arow = (MODE == 0) ? (size_t)rows[grow] : (size_t)(grow - c0);
      aoff[qm][i] = arow * (size_t)Astride;
    }
  size_t boff[2][2];
#pragma unroll
  for (int qn = 0; qn < 2; ++qn)
#pragma unroll
    for (int i = 0; i < 2; ++i) {
      int rl = i * 64 + (tid >> 3);
      int brow = (rl >> 5) * 64 + qn * 32 + (rl & 31);
      boff[qn][i] = ((size_t)e * N + (size_t)(tn * 256 + brow)) * (size_t)K;
    }

  const int nt = K >> 6;
  // prologue stream: SB0(0),SA0(0),SB1(0),SA1(0),SB0(1),SA0(1); vmcnt(8): t0.q0 ready
  SB_Q(0, 0, 0); SA_Q(0, 0, 0); SB_Q(0, 1, 0); SA_Q(0, 1, 0);
  SB_Q(1, 0, 1); SA_Q(1, 0, 1);
  PH_END(8);

  for (int t = 0; t < nt; ++t) {
    const int b = t & 1;
    const unsigned short* ldsAb = lds + b * 16384;
    const unsigned short* ldsBb = lds + 32768 + b * 16384;
    const bool tw = (t + 2 >= nt);
    short8 af0[4][2], af1[4][2], bf0[2][2], bf1[2][2];
    // P0: read af0+bf0; stage SB1(t+1)->b^1; MFMA q00
    LOAD_AFH(af0, 0); LOAD_BFH(bf0, 0);
    if (t + 1 < nt) SB_Q(b ^ 1, 1, t + 1);
    BARRIER();
    MFMA_Q(0, 0, af0, bf0);
    if (tw) PH_END(0); else PH_END(8);
    // P1: read bf1; stage SA1(t+1)->b^1; MFMA q01 (af0 held)
    LOAD_BFH(bf1, 1);
    if (t + 1 < nt) SA_Q(b ^ 1, 1, t + 1);
    BARRIER();
    MFMA_Q(0, 1, af0, bf1);
    if (tw) PH_END(0); else PH_END(8);
    // P2: read af1; stage SB0(t+2)->b (B.qn0 dead since P0); MFMA q11 (bf1 held)
    LOAD_AFH(af1, 1);
    if (!tw) SB_Q(b, 0, t + 2);
    BARRIER();
    MFMA_Q(1, 1, af1, bf1);
    asm volatile("s_waitcnt lgkmcnt(0)" ::: "memory");
    BARRIER();
    // P3: stage SA0(t+2)->b (A.qm0 dead since P0); MFMA q10 (af1, bf0 held)
    if (!tw) SA_Q(b, 0, t + 2);
    BARRIER();
    MFMA_Q(1, 0, af1, bf0);
    if (tw) PH_END(0); else PH_END(8);
  }

  if (MODE == 2) {
    // fallback: scattered f32 atomics into d_out
#pragma unroll
    for (int mi = 0; mi < 8; ++mi) {
      int g = rowbase + wm * 128 + mi * 16 + l15;
      int token = rows[g];
      float wgt = roww[g];
#pragma unroll
      for (int ni = 0; ni < 4; ++ni) {
        int n = tn * 256 + wn * 64 + ni * 16 + lh * 4;
        f32x4 v = acc[mi][ni];
        f32x4 bv = *(const f32x4*)(bias + (size_t)e * N + n);
#pragma unroll
        for (int qd = 0; qd < 4; ++qd)
          atomicAdd(&Of[(size_t)token * N + n + qd], wgt * (v[qd] + bv[qd]));
      }
    }
    return;
  }

  // epilogue: acc -> swizzled fp16 tile in LDS (reuse staging LDS) -> coalesced stores
  __syncthreads();
#pragma unroll
  for (int mi = 0; mi < 8; ++mi) {
    const int row = wm * 128 + mi * 16 + l15;
    float wgt = 1.0f;
    if (MODE == 3) wgt = roww[rowbase + row];
#pragma unroll
    for (int ni = 0; ni < 4; ++ni) {
      const int col = wn * 64 + ni * 16 + lh * 4;
      f32x4 v = acc[mi][ni];
      f32x4 bv = *(const f32x4*)(bias + (size_t)e * N + tn * 256 + col);
      u16x4 h;
#pragma unroll
      for (int qd = 0; qd < 4; ++qd) {
        float vv = v[qd] + bv[qd];
        if (MODE == 3) vv *= wgt;
        h[qd] = f2h(vv);
      }
      const int ch = (col >> 3) ^ (row & 7);
      *(u16x4*)(lds + row * 256 + ch * 8 + (col & 7)) = h;
    }
  }
  __syncthreads();
#pragma unroll
  for (int it = 0; it < 16; ++it) {
    const int flat = it * 512 + tid;
    const int row = flat >> 5;              // 0..255
    const int ch = flat & 31;               // 32 x 16B = full 512B row
    const int chs = ch ^ (row & 7);
    short8 v = *(const short8*)(lds + row * 256 + chs * 8);
    const int g = rowbase + row;
    unsigned short* dst = (MODE == 3) ? (Oh + (size_t)g * N)
                                      : (Oh + (size_t)(g - c0) * N);
    *(short8*)(dst + tn * 256 + ch * 8) = v;
  }
}

// ---------------- LayerNorm + exact GELU: fp16 in, fp16 out (f32 stats) ------
__global__ __launch_bounds__(256) void ln_gelu_kernel(
    const unsigned short* __restrict__ src, unsigned short* __restrict__ dst,
    const float* __restrict__ gam, const float* __restrict__ bet,
    const int* __restrict__ off, const int c0)
{
  const int g = c0 + blockIdx.x;
  if (g >= off[NEXP]) return;
  int e = 0;
#pragma unroll
  for (int q = 1; q < NEXP; ++q) if (g >= off[q]) e = q;
  const int tid = threadIdx.x;
  const unsigned short* s0 = src + (size_t)(g - c0) * HID;
  short8 hv = *(const short8*)(s0 + tid * 8);
  float v[8];
  float s = 0.f, sq = 0.f;
#pragma unroll
  for (int q = 0; q < 8; ++q) {
    v[q] = h2f((unsigned short)hv[q]);
    s += v[q]; sq += v[q] * v[q];
  }
#pragma unroll
  for (int sh = 32; sh > 0; sh >>= 1) { s += __shfl_xor(s, sh); sq += __shfl_xor(sq, sh); }
  __shared__ float rs_[4], rq_[4];
  const int lane = tid & 63, wid = tid >> 6;
  if (lane == 0) { rs_[wid] = s; rq_[wid] = sq; }
  __syncthreads();
  s  = rs_[0] + rs_[1] + rs_[2] + rs_[3];
  sq = rq_[0] + rq_[1] + rq_[2] + rq_[3];
  const float mu  = s * (1.0f / HID);
  const float var = sq * (1.0f / HID) - mu * mu;
  const float rstd = rsqrtf(var + 1e-5f);
  const float* gp = gam + (size_t)e * HID + tid * 8;
  const float* bp = bet + (size_t)e * HID + tid * 8;
  short8 o;
#pragma unroll
  for (int q = 0; q < 8; ++q) {
    float t = (v[q] - mu) * rstd * gp[q] + bp[q];
    o[q] = (short)f2h(gelu_exact(t));
  }
  *(short8*)(dst + (size_t)(g - c0) * HID + tid * 8) = o;
}

// ---------------- deterministic 2-row combine (fp16 Y -> f32 out) ------------
__global__ __launch_bounds__(256) void combine_kernel(
    const unsigned short* __restrict__ Y, const int* __restrict__ pair,
    float* __restrict__ out)
{
  const int n = blockIdx.x;
  const int j = threadIdx.x * 4;
  const int r1 = pair[2 * n], r2 = pair[2 * n + 1];
  u16x4 a = *(const u16x4*)(Y + (size_t)r1 * OUTD + j);
  u16x4 b = *(const u16x4*)(Y + (size_t)r2 * OUTD + j);
  f32x4 o;
#pragma unroll
  for (int qd = 0; qd < 4; ++qd) o[qd] = h2f(a[qd]) + h2f(b[qd]);
  *(f32x4*)(out + (size_t)n * OUTD + j) = o;
}

// fallback diagnostic: encode ws_size (MB) into out[0]
__global__ void probe_kernel(float* out, float v) {
  if (threadIdx.x == 0 && blockIdx.x == 0) out[0] = v;
}

extern "C" void kernel_launch(void* const* d_in, const int* in_sizes, int n_in,
                              void* d_out, int out_size, void* d_ws, size_t ws_size,
                              hipStream_t stream) {
  (void)in_sizes; (void)n_in;
  const float* x   = (const float*)d_in[0];
  const float* Wg1 = (const float*)d_in[1];
  const float* Wg2 = (const float*)d_in[2];
  const float* W1  = (const float*)d_in[3];
  const float* b1  = (const float*)d_in[4];
  const float* g1  = (const float*)d_in[5];
  const float* be1 = (const float*)d_in[6];
  const float* W2  = (const float*)d_in[7];
  const float* b2  = (const float*)d_in[8];
  const float* g2  = (const float*)d_in[9];
  const float* be2 = (const float*)d_in[10];
  const float* W3  = (const float*)d_in[11];
  const float* b3  = (const float*)d_in[12];
  float* out = (float*)d_out;

  uint8_t* w = (uint8_t*)d_ws;
  auto alloc = [&](size_t bytes) {
    uint8_t* p = w;
    w += (bytes + 255) & ~(size_t)255;
    return p;
  };
  unsigned short* xh   = (unsigned short*)alloc((size_t)N_TOK * DIM * 2);
  unsigned short* Wt1  = (unsigned short*)alloc((size_t)NEXP * DIM * HID * 2);
  unsigned short* Wt2  = (unsigned short*)alloc((size_t)NEXP * HID * HID * 2);
  unsigned short* Wt3  = (unsigned short*)alloc((size_t)NEXP * HID * OUTD * 2);
  int*   rows  = (int*)alloc((size_t)PADTOT * 4);
  float* roww  = (float*)alloc((size_t)PADTOT * 4);
  int*   tok_e = (int*)alloc((size_t)2 * N_TOK * 4);
  float* tok_w = (float*)alloc((size_t)2 * N_TOK * 4);
  int*   pair  = (int*)alloc((size_t)2 * N_TOK * 4);
  int*   cnt   = (int*)alloc(256);
  int*   off   = (int*)alloc(256);
  int*   cur   = (int*)alloc(256);
  size_t fixed_used = (size_t)(w - (uint8_t*)d_ws);

  // adaptive chunk rows: act1h (fp16) + act2 (fp16) = 8192 B/row, 256-row granules
  long long availLL = (long long)ws_size - (long long)fixed_used - 4096;
  int R = 0;
  if (availLL > 0) {
    long long r = availLL / (HID * 2 + HID * 2);
    if (r > PADTOT) r = PADTOT;
    R = (int)(r & ~255LL);
  }
  if (R < 256) {   // diagnostic fallback: out[0] = ws_size in MB
    hipMemsetAsync(d_out, 0, (size_t)out_size * sizeof(float), stream);
    probe_kernel<<<1, 64, 0, stream>>>(out, (float)(ws_size >> 20));
    return;
  }
  unsigned short* act1h = (unsigned short*)alloc((size_t)R * HID * 2);
  unsigned short* act2  = (unsigned short*)alloc((size_t)R * HID * 2);
  const bool single = (R >= PADTOT);   // Y (fp16 [PADTOT][1024]) aliases act1h
  unsigned short* Yh = act1h;

  hipMemsetAsync(cnt, 0, NEXP * sizeof(int), stream);
  hipMemsetAsync(rows, 0, (size_t)PADTOT * 4, stream);   // dummy rows -> token 0
  hipMemsetAsync(roww, 0, (size_t)PADTOT * 4, stream);   // dummy weight -> 0.0
  if (!single)
    hipMemsetAsync(d_out, 0, (size_t)out_size * sizeof(float), stream);  // atomic target

  gate_kernel<<<N_TOK / 8, 256, 0, stream>>>(x, Wg1, Wg2, tok_e, tok_w);
  hist_kernel<<<2 * N_TOK / 512, 256, 0, stream>>>(tok_e, cnt);
  offsets_kernel<<<1, 64, 0, stream>>>(cnt, off, cur);
  scatter_kernel<<<N_TOK / 256, 256, 0, stream>>>(tok_e, tok_w, cur, rows, roww, pair);

  convert_x_kernel<<<(N_TOK * DIM / 8) / 256, 256, 0, stream>>>(x, xh);
  wconv_kernel<<<dim3(HID / 32, DIM / 32, NEXP), 256, 0, stream>>>(W1, Wt1, DIM, HID);
  wconv_kernel<<<dim3(HID / 32, HID / 32, NEXP), 256, 0, stream>>>(W2, Wt2, HID, HID);
  wconv_kernel<<<dim3(OUTD / 32, HID / 32, NEXP), 256, 0, stream>>>(W3, Wt3, HID, OUTD);

  for (int c0 = 0; c0 < PADTOT; c0 += R) {
    int Rc = PADTOT - c0; if (Rc > R) Rc = R;
    const int yt = Rc / 256;
    gemm256_kernel<0><<<8 * yt, 512, 0, stream>>>(xh, Wt1, act1h, nullptr, b1,
                                                  rows, roww, off, DIM, HID, DIM, c0, 3);
    ln_gelu_kernel<<<Rc, 256, 0, stream>>>(act1h, act2, g1, be1, off, c0);
    gemm256_kernel<1><<<8 * yt, 512, 0, stream>>>(act2, Wt2, act1h, nullptr, b2,
                                                  rows, roww, off, HID, HID, HID, c0, 3);
    ln_gelu_kernel<<<Rc, 256, 0, stream>>>(act1h, act2, g2, be2, off, c0);
    if (single)
      gemm256_kernel<3><<<4 * yt, 512, 0, stream>>>(act2, Wt3, Yh, nullptr, b3,
                                                    rows, roww, off, HID, OUTD, HID, c0, 2);
    else
      gemm256_kernel<2><<<4 * yt, 512, 0, stream>>>(act2, Wt3, nullptr, out, b3,
                                                    rows, roww, off, HID, OUTD, HID, c0, 2);
  }
  if (single)
    combine_kernel<<<N_TOK, 256, 0, stream>>>(Yh, pair, out);
}

// Round 12
// 1009.768 us; speedup vs baseline: 1.4534x; 1.4534x over previous
//
#include <hip/hip_runtime.h>
#include <math.h>
#include <stdint.h>

#define N_TOK 16384
#define DIM   1024
#define NEXP  8
#define HID   2048
#define OUTD  1024
#define PADTOT 34816   // 2*N_TOK + 8*256 : padded compacted-row upper bound (136 tiles of 256)

typedef __attribute__((ext_vector_type(8))) short short8;
typedef __attribute__((ext_vector_type(8))) _Float16 f16x8;
typedef __attribute__((ext_vector_type(4))) float f32x4;
typedef __attribute__((ext_vector_type(4))) unsigned short u16x4;

__device__ __forceinline__ unsigned short f2h(float f) {
  return __builtin_bit_cast(unsigned short, (_Float16)f);   // RNE
}
__device__ __forceinline__ float h2f(unsigned short h) {
  return (float)__builtin_bit_cast(_Float16, h);
}
__device__ __forceinline__ float gelu_exact(float a) {
  return 0.5f * a * (1.0f + erff(a * 0.70710678118654752f));
}

// ---- prep: Wg1 [1024][16] f32 -> Wg1t [256][16][4] f32 (d0-major, j, d-low) ----
__global__ __launch_bounds__(256) void wg1t_kernel(
    const float* __restrict__ Wg1, float* __restrict__ Wg1t)
{
  const int t = blockIdx.x * 256 + threadIdx.x;   // 4096 threads: (d0, j)
  const int d0 = t >> 4, j = t & 15;
  f32x4 v;
#pragma unroll
  for (int c = 0; c < 4; ++c) v[c] = Wg1[(size_t)(d0 * 4 + c) * 16 + j];
  *(f32x4*)(Wg1t + (size_t)d0 * 64 + j * 4) = v;
}

// ---------------- gate v3: lane-owns-logit, fp64, 2-stage reduce --------------
// lane = 16*(d-stripe g4) + logit j.  Per token: 64 iters x 4 fp64 FMA; reduce
// over g4 = shfl_xor 16,32 (2 stages).  Epilogue per-wave (2 tokens/wave).
__global__ __launch_bounds__(256) void gate_kernel(
    const float* __restrict__ x, const float* __restrict__ Wg1t,
    const float* __restrict__ Wg2,
    int* __restrict__ tok_e, float* __restrict__ tok_w)
{
  const int tid = threadIdx.x;
  const int lane = tid & 63, wid = tid >> 6;
  const int j = lane & 15, g4 = lane >> 4;
  for (int tk = 0; tk < 2; ++tk) {
    const int n = blockIdx.x * 8 + wid * 2 + tk;
    const float* xrow = x + (size_t)n * DIM;
    double acc = 0.0;
    for (int it = 0; it < DIM / 16; ++it) {
      f32x4 xq = *(const f32x4*)(xrow + it * 16 + g4 * 4);          // 16-lane bcast
      f32x4 wq = *(const f32x4*)(Wg1t + ((size_t)it * 4 + g4) * 64 + j * 4); // coalesced
#pragma unroll
      for (int c = 0; c < 4; ++c)
        acc += (double)xq[c] * (double)wq[c];
    }
    acc += __shfl_xor(acc, 16);
    acc += __shfl_xor(acc, 32);       // every lane: full logit (lane&15) sum
    double t = tanh(acc);
    const int e = lane & 7;
    double ge = 0.0;
#pragma unroll
    for (int jj = 0; jj < 16; ++jj) {
      double tj = __shfl(t, jj);
      ge += tj * (double)Wg2[jj * 8 + e];
    }
    // softmax over 8 within each 8-lane group
    double m = ge;
#pragma unroll
    for (int s = 1; s < 8; s <<= 1) m = fmax(m, __shfl_xor(m, s));
    double p = exp(ge - m);
    double ssum = p;
#pragma unroll
    for (int s = 1; s < 8; s <<= 1) ssum += __shfl_xor(ssum, s);
    double wsm = p / ssum;
    // top-2 via 64-bit keys (ties -> lowest index, like lax.top_k)
    unsigned long long key =
        (((unsigned long long)__double_as_longlong(wsm)) & ~7ULL) |
        (unsigned long long)(7 - e);
    unsigned long long k1 = key;
#pragma unroll
    for (int s = 1; s < 8; s <<= 1) { unsigned long long o = __shfl_xor(k1, s); k1 = (o > k1) ? o : k1; }
    int e1 = 7 - (int)(k1 & 7ULL);
    unsigned long long k2 = (e == e1) ? 0ULL : key;
#pragma unroll
    for (int s = 1; s < 8; s <<= 1) { unsigned long long o = __shfl_xor(k2, s); k2 = (o > k2) ? o : k2; }
    int e2 = 7 - (int)(k2 & 7ULL);
    double w1v = __longlong_as_double((long long)(k1 & ~7ULL));
    double w2v = __longlong_as_double((long long)(k2 & ~7ULL));
    double inv = 1.0 / (w1v + w2v + 1e-12);
    if (lane == 0) {
      tok_e[2 * n] = e1; tok_e[2 * n + 1] = e2;
      tok_w[2 * n] = (float)(w1v * inv); tok_w[2 * n + 1] = (float)(w2v * inv);
    }
  }
}

// ---------------- hist: LDS histogram, 8 global atomics per block ------------
__global__ __launch_bounds__(256) void hist_kernel(
    const int* __restrict__ tok_e, int* __restrict__ cnt)
{
  __shared__ int h[NEXP];
  const int tid = threadIdx.x;
  if (tid < NEXP) h[tid] = 0;
  __syncthreads();
  const int base = blockIdx.x * 512;
  atomicAdd(&h[tok_e[base + tid]], 1);
  atomicAdd(&h[tok_e[base + 256 + tid]], 1);
  __syncthreads();
  if (tid < NEXP) atomicAdd(&cnt[tid], h[tid]);
}

// offsets padded to multiples of 256 so every 256-row tile is single-expert
__global__ void offsets_kernel(const int* __restrict__ cnt, int* __restrict__ off,
                               int* __restrict__ cur) {
  if (threadIdx.x == 0) {
    int a = 0;
    for (int e = 0; e < NEXP; ++e) {
      off[e] = a; cur[e] = a;
      a += (cnt[e] + 255) & ~255;
    }
    off[NEXP] = a;
  }
}

// ---------------- scatter: per-block LDS rank + one base-claim per expert ----
__global__ __launch_bounds__(256) void scatter_kernel(
    const int* __restrict__ tok_e, const float* __restrict__ tok_w,
    int* __restrict__ cur, int* __restrict__ rows, float* __restrict__ roww,
    int* __restrict__ pair)
{
  __shared__ int lcnt[NEXP];
  __shared__ int lbase[NEXP];
  const int tid = threadIdx.x;
  if (tid < NEXP) lcnt[tid] = 0;
  __syncthreads();
  const int n = blockIdx.x * 256 + tid;
  const int e0 = tok_e[2 * n], e1 = tok_e[2 * n + 1];
  const int r0 = atomicAdd(&lcnt[e0], 1);
  const int r1 = atomicAdd(&lcnt[e1], 1);
  __syncthreads();
  if (tid < NEXP) lbase[tid] = atomicAdd(&cur[tid], lcnt[tid]);
  __syncthreads();
  const int p0 = lbase[e0] + r0;
  const int p1 = lbase[e1] + r1;
  rows[p0] = n; roww[p0] = tok_w[2 * n];     pair[2 * n]     = p0;
  rows[p1] = n; roww[p1] = tok_w[2 * n + 1]; pair[2 * n + 1] = p1;
}

// ---------------- fp32 -> fp16 converts ----------------
__global__ __launch_bounds__(256) void convert_x_kernel(
    const float* __restrict__ x, unsigned short* __restrict__ xh)
{
  size_t i = ((size_t)blockIdx.x * 256 + threadIdx.x) * 8;
  f32x4 a = *(const f32x4*)(x + i);
  f32x4 b = *(const f32x4*)(x + i + 4);
  short8 o;
#pragma unroll
  for (int q = 0; q < 4; ++q) { o[q] = (short)f2h(a[q]); o[q + 4] = (short)f2h(b[q]); }
  *(short8*)(xh + i) = o;
}

// transpose+convert: W[e][K][N] fp32 -> Wt[e][N][K] fp16.  64x64 tiles, 16/thread.
__global__ __launch_bounds__(256) void wconv_kernel(
    const float* __restrict__ W, unsigned short* __restrict__ Wt,
    const int K, const int N)
{
  __shared__ float t[64][65];
  const int e = blockIdx.z;
  const float* We = W + (size_t)e * K * N;
  unsigned short* Wte = Wt + (size_t)e * K * N;
  const int n0 = blockIdx.x * 64, k0 = blockIdx.y * 64;
  const int tid = threadIdx.x;
  const int rr0 = tid >> 4, c4 = (tid & 15) * 4;
#pragma unroll
  for (int rr = 0; rr < 4; ++rr) {
    const int r = rr * 16 + rr0;
    f32x4 v = *(const f32x4*)(We + (size_t)(k0 + r) * N + n0 + c4);
    t[r][c4 + 0] = v[0]; t[r][c4 + 1] = v[1]; t[r][c4 + 2] = v[2]; t[r][c4 + 3] = v[3];
  }
  __syncthreads();
#pragma unroll
  for (int rr = 0; rr < 4; ++rr) {
    const int nn = rr * 16 + rr0;
    u16x4 o;
#pragma unroll
    for (int q = 0; q < 4; ++q) o[q] = f2h(t[c4 + q][nn]);
    *(u16x4*)(Wte + (size_t)(n0 + nn) * K + k0 + c4) = o;
  }
}

// ============ 256x256 8-wave routed GEMM, 2-barrier/K-tile, fragment-reuse ============
// (round-10 proven structure: 324 us stage-2, MfmaUtil 40%)
// Per tile: STAGEA(t+1); read af0+bf; 32 MFMA; lgkm0+bar; STAGEB(t+2); read af1;
// 32 MFMA; vmcnt(4)+lgkm0+bar.
// MODE 0: A = gathered xh rows; MODE 1: A = act2; MODE 2: atomic fallback; MODE 3: Y out.

#define STAGEA(SB_, T_) do {                                                  \
  _Pragma("unroll") for (int qm_ = 0; qm_ < 2; ++qm_)                         \
  _Pragma("unroll") for (int i_ = 0; i_ < 2; ++i_)                            \
    __builtin_amdgcn_global_load_lds(                                         \
      (const __attribute__((address_space(1))) void*)(Abase + aoff[qm_][i_] + (size_t)(T_)*64 + kc8), \
      (__attribute__((address_space(3))) void*)(lds + (SB_)*16384 + qm_*4096 + i_*8192 + tid*8), \
      16, 0, 0);                                                              \
} while (0)

// dest = B + qn*2048 + (i*2 + (tid>>8))*4096 + (tid&255)*8   [round-8 verified layout]
#define STAGEB(SB_, T_) do {                                                  \
  _Pragma("unroll") for (int qn_ = 0; qn_ < 2; ++qn_)                         \
  _Pragma("unroll") for (int i_ = 0; i_ < 2; ++i_)                            \
    __builtin_amdgcn_global_load_lds(                                         \
      (const __attribute__((address_space(1))) void*)(Bbase + boff[qn_][i_] + (size_t)(T_)*64 + kc8), \
      (__attribute__((address_space(3))) void*)(lds + 32768 + (SB_)*16384 + qn_*2048 + (i_*2 + (tid >> 8))*4096 + (tid & 255)*8), \
      16, 0, 0);                                                              \
} while (0)

#define LOAD_AF(QM_) do {                                                     \
    _Pragma("unroll") for (int mi = 0; mi < 4; ++mi)                          \
    _Pragma("unroll") for (int kk = 0; kk < 2; ++kk) {                        \
      const int row_ = wm*128 + (QM_)*64 + mi*16 + l15;                       \
      const int ch_ = ((kk*4 + lh) ^ (row_ & 7));                             \
      af[mi][kk] = *(const short8*)(ldsAb + row_*64 + ch_*8);                 \
    }                                                                         \
} while (0)

#define LOAD_BF() do {                                                        \
    _Pragma("unroll") for (int qn = 0; qn < 2; ++qn)                          \
    _Pragma("unroll") for (int ni = 0; ni < 2; ++ni)                          \
    _Pragma("unroll") for (int kk = 0; kk < 2; ++kk) {                        \
      const int row_ = wn*64 + qn*32 + ni*16 + l15;                           \
      const int ch_ = ((kk*4 + lh) ^ (row_ & 7));                             \
      bf[qn][ni][kk] = *(const short8*)(ldsBb + row_*64 + ch_*8);             \
    }                                                                         \
} while (0)

// 32 MFMA: half QM_ x all 4 column-fragments x K=64
#define MFMA_HALF(QM_) do {                                                   \
    __builtin_amdgcn_s_setprio(1);                                            \
    _Pragma("unroll") for (int kk = 0; kk < 2; ++kk)                          \
    _Pragma("unroll") for (int mi = 0; mi < 4; ++mi)                          \
    _Pragma("unroll") for (int qn = 0; qn < 2; ++qn)                          \
    _Pragma("unroll") for (int ni = 0; ni < 2; ++ni)                          \
      acc[(QM_)*4 + mi][qn*2 + ni] = __builtin_amdgcn_mfma_f32_16x16x32_f16(  \
          __builtin_bit_cast(f16x8, bf[qn][ni][kk]),                          \
          __builtin_bit_cast(f16x8, af[mi][kk]),                              \
          acc[(QM_)*4 + mi][qn*2 + ni], 0, 0, 0);                             \
    __builtin_amdgcn_s_setprio(0);                                            \
} while (0)

#define SYNC_LGKM_BAR() do {                                                  \
  asm volatile("s_waitcnt lgkmcnt(0)" ::: "memory");                          \
  asm volatile("s_barrier" ::: "memory");                                     \
} while (0)
#define PH_END(N_) do {                                                       \
  asm volatile("s_waitcnt vmcnt(" #N_ ") lgkmcnt(0)" ::: "memory");           \
  asm volatile("s_barrier" ::: "memory");                                     \
} while (0)

template<int MODE>
__global__ __launch_bounds__(512, 1) void gemm256_kernel(
    const unsigned short* __restrict__ Abase,
    const unsigned short* __restrict__ Bbase,
    unsigned short* __restrict__ Oh,
    float* __restrict__ Of,
    const float* __restrict__ bias,
    const int* __restrict__ rows,
    const float* __restrict__ roww,
    const int* __restrict__ off,
    const int K, const int N, const int Astride, const int c0, const int lgGX)
{
  // XCD-chunked bijective block remap (m204)
  const unsigned orig = blockIdx.x, nwg = gridDim.x;
  const unsigned q8 = nwg >> 3, r8 = nwg & 7;
  const unsigned xcd = orig & 7, pos = orig >> 3;
  const unsigned wrk = (xcd < r8 ? xcd * (q8 + 1) : r8 * (q8 + 1) + (xcd - r8) * q8) + pos;
  const int tn = (int)(wrk & ((1u << lgGX) - 1u));
  const int rowbase = c0 + (int)(wrk >> lgGX) * 256;

  const int off8 = off[NEXP];
  if (rowbase >= off8) return;
  int e = 0;
  while (e < NEXP - 1 && rowbase >= off[e + 1]) ++e;

  // LDS: A[2 buf][256][64] fp16 @0, B[2 buf][256][64] fp16 @32768 shorts = 128 KiB
  __shared__ __align__(16) unsigned short lds[65536];

  const int tid = threadIdx.x, lane = tid & 63, wid = tid >> 6;
  const int wm = wid >> 2, wn = wid & 3;       // 2 x 4 waves, each owns 128x64
  const int l15 = lane & 15, lh = lane >> 4;
  const int kc8 = ((tid & 7) ^ ((tid >> 3) & 7)) * 8;   // pre-swizzled source chunk

  f32x4 acc[8][4] = {};

  size_t aoff[2][2];
#pragma unroll
  for (int qm = 0; qm < 2; ++qm)
#pragma unroll
    for (int i = 0; i < 2; ++i) {
      int grow = rowbase + i * 128 + qm * 64 + (tid >> 3);
      size_t arow = (MODE == 0) ? (size_t)rows[grow] : (size_t)(grow - c0);
      aoff[qm][i] = arow * (size_t)Astride;
    }
  size_t boff[2][2];
#pragma unroll
  for (int qn = 0; qn < 2; ++qn)
#pragma unroll
    for (int i = 0; i < 2; ++i) {
      int rl = i * 64 + (tid >> 3);
      int brow = (rl >> 5) * 64 + qn * 32 + (rl & 31);
      boff[qn][i] = ((size_t)e * N + (size_t)(tn * 256 + brow)) * (size_t)K;
    }

  const int nt = K >> 6;
  // prologue: SA(0), SB(0) into buf0; SB(1) into buf1.  vmcnt(4): t0 A+B done.
  STAGEA(0, 0); STAGEB(0, 0); STAGEB(1, 1);
  PH_END(4);

  for (int t = 0; t < nt; ++t) {
    const int b = t & 1;
    const unsigned short* ldsAb = lds + b * 16384;
    const unsigned short* ldsBb = lds + 32768 + b * 16384;
    short8 af[4][2], bf[2][2][2];
    if (t + 1 < nt) STAGEA(b ^ 1, t + 1);
    LOAD_AF(0); LOAD_BF();
    MFMA_HALF(0);
    SYNC_LGKM_BAR();                 // all waves' B[b]/A[b]-top reads complete
    if (t + 2 < nt) STAGEB(b, t + 2);
    LOAD_AF(1);
    MFMA_HALF(1);
    if (t + 2 < nt) PH_END(4); else PH_END(0);   // SA(t+1)+SB(t+1) complete
  }

  if (MODE == 2) {
#pragma unroll
    for (int mi = 0; mi < 8; ++mi) {
      int g = rowbase + wm * 128 + mi * 16 + l15;
      int token = rows[g];
      float wgt = roww[g];
#pragma unroll
      for (int ni = 0; ni < 4; ++ni) {
        int n = tn * 256 + wn * 64 + ni * 16 + lh * 4;
        f32x4 v = acc[mi][ni];
        f32x4 bv = *(const f32x4*)(bias + (size_t)e * N + n);
#pragma unroll
        for (int qd = 0; qd < 4; ++qd)
          atomicAdd(&Of[(size_t)token * N + n + qd], wgt * (v[qd] + bv[qd]));
      }
    }
    return;
  }

  // epilogue: acc -> swizzled fp16 tile in LDS -> coalesced stores
  __syncthreads();
#pragma unroll
  for (int mi = 0; mi < 8; ++mi) {
    const int row = wm * 128 + mi * 16 + l15;
    float wgt = 1.0f;
    if (MODE == 3) wgt = roww[rowbase + row];
#pragma unroll
    for (int ni = 0; ni < 4; ++ni) {
      const int col = wn * 64 + ni * 16 + lh * 4;
      f32x4 v = acc[mi][ni];
      f32x4 bv = *(const f32x4*)(bias + (size_t)e * N + tn * 256 + col);
      u16x4 h;
#pragma unroll
      for (int qd = 0; qd < 4; ++qd) {
        float vv = v[qd] + bv[qd];
        if (MODE == 3) vv *= wgt;
        h[qd] = f2h(vv);
      }
      const int ch = (col >> 3) ^ (row & 7);
      *(u16x4*)(lds + row * 256 + ch * 8 + (col & 7)) = h;
    }
  }
  __syncthreads();
#pragma unroll
  for (int it = 0; it < 16; ++it) {
    const int flat = it * 512 + tid;
    const int row = flat >> 5;
    const int ch = flat & 31;
    const int chs = ch ^ (row & 7);
    short8 v = *(const short8*)(lds + row * 256 + chs * 8);
    const int g = rowbase + row;
    unsigned short* dst = (MODE == 3) ? (Oh + (size_t)g * N)
                                      : (Oh + (size_t)(g - c0) * N);
    *(short8*)(dst + tn * 256 + ch * 8) = v;
  }
}

// ---------------- LN + exact GELU: wave-per-row, no LDS, no block sync -------
__global__ __launch_bounds__(256) void ln_gelu_kernel(
    const unsigned short* __restrict__ src, unsigned short* __restrict__ dst,
    const float* __restrict__ gam, const float* __restrict__ bet,
    const int* __restrict__ off, const int c0)
{
  const int wid = threadIdx.x >> 6, lane = threadIdx.x & 63;
  const int g = c0 + blockIdx.x * 4 + wid;
  if (g >= off[NEXP]) return;
  int e = 0;
#pragma unroll
  for (int q = 1; q < NEXP; ++q) if (g >= off[q]) e = q;
  const unsigned short* s0 = src + (size_t)(g - c0) * HID;
  float v[32];
  float s = 0.f, sq = 0.f;
#pragma unroll
  for (int ch = 0; ch < 4; ++ch) {
    short8 hv = *(const short8*)(s0 + ch * 512 + lane * 8);
#pragma unroll
    for (int q = 0; q < 8; ++q) {
      float f = h2f((unsigned short)hv[q]);
      v[ch * 8 + q] = f;
      s += f; sq += f * f;
    }
  }
#pragma unroll
  for (int sh = 32; sh > 0; sh >>= 1) { s += __shfl_xor(s, sh); sq += __shfl_xor(sq, sh); }
  const float mu  = s * (1.0f / HID);
  const float var = sq * (1.0f / HID) - mu * mu;
  const float rstd = rsqrtf(var + 1e-5f);
  const float* ge_ = gam + (size_t)e * HID;
  const float* be_ = bet + (size_t)e * HID;
  unsigned short* d0 = dst + (size_t)(g - c0) * HID;
#pragma unroll
  for (int ch = 0; ch < 4; ++ch) {
    const int base = ch * 512 + lane * 8;
    f32x4 ga = *(const f32x4*)(ge_ + base);
    f32x4 gb = *(const f32x4*)(ge_ + base + 4);
    f32x4 ba = *(const f32x4*)(be_ + base);
    f32x4 bb = *(const f32x4*)(be_ + base + 4);
    short8 o;
#pragma unroll
    for (int q = 0; q < 4; ++q) {
      float t1 = (v[ch * 8 + q] - mu) * rstd * ga[q] + ba[q];
      float t2 = (v[ch * 8 + 4 + q] - mu) * rstd * gb[q] + bb[q];
      o[q] = (short)f2h(gelu_exact(t1));
      o[q + 4] = (short)f2h(gelu_exact(t2));
    }
    *(short8*)(d0 + base) = o;
  }
}

// ---------------- deterministic 2-row combine (fp16 Y -> f32 out) ------------
__global__ __launch_bounds__(256) void combine_kernel(
    const unsigned short* __restrict__ Y, const int* __restrict__ pair,
    float* __restrict__ out)
{
  const int n = blockIdx.x;
  const int j = threadIdx.x * 4;
  const int r1 = pair[2 * n], r2 = pair[2 * n + 1];
  u16x4 a = *(const u16x4*)(Y + (size_t)r1 * OUTD + j);
  u16x4 b = *(const u16x4*)(Y + (size_t)r2 * OUTD + j);
  f32x4 o;
#pragma unroll
  for (int qd = 0; qd < 4; ++qd) o[qd] = h2f(a[qd]) + h2f(b[qd]);
  *(f32x4*)(out + (size_t)n * OUTD + j) = o;
}

// fallback diagnostic: encode ws_size (MB) into out[0]
__global__ void probe_kernel(float* out, float v) {
  if (threadIdx.x == 0 && blockIdx.x == 0) out[0] = v;
}

extern "C" void kernel_launch(void* const* d_in, const int* in_sizes, int n_in,
                              void* d_out, int out_size, void* d_ws, size_t ws_size,
                              hipStream_t stream) {
  (void)in_sizes; (void)n_in;
  const float* x   = (const float*)d_in[0];
  const float* Wg1 = (const float*)d_in[1];
  const float* Wg2 = (const float*)d_in[2];
  const float* W1  = (const float*)d_in[3];
  const float* b1  = (const float*)d_in[4];
  const float* g1  = (const float*)d_in[5];
  const float* be1 = (const float*)d_in[6];
  const float* W2  = (const float*)d_in[7];
  const float* b2  = (const float*)d_in[8];
  const float* g2  = (const float*)d_in[9];
  const float* be2 = (const float*)d_in[10];
  const float* W3  = (const float*)d_in[11];
  const float* b3  = (const float*)d_in[12];
  float* out = (float*)d_out;

  uint8_t* w = (uint8_t*)d_ws;
  auto alloc = [&](size_t bytes) {
    uint8_t* p = w;
    w += (bytes + 255) & ~(size_t)255;
    return p;
  };
  unsigned short* xh   = (unsigned short*)alloc((size_t)N_TOK * DIM * 2);
  unsigned short* Wt1  = (unsigned short*)alloc((size_t)NEXP * DIM * HID * 2);
  unsigned short* Wt2  = (unsigned short*)alloc((size_t)NEXP * HID * HID * 2);
  unsigned short* Wt3  = (unsigned short*)alloc((size_t)NEXP * HID * OUTD * 2);
  float* Wg1t  = (float*)alloc((size_t)DIM * 16 * 4);
  int*   rows  = (int*)alloc((size_t)PADTOT * 4);
  float* roww  = (float*)alloc((size_t)PADTOT * 4);
  int*   tok_e = (int*)alloc((size_t)2 * N_TOK * 4);
  float* tok_w = (float*)alloc((size_t)2 * N_TOK * 4);
  int*   pair  = (int*)alloc((size_t)2 * N_TOK * 4);
  int*   cnt   = (int*)alloc(256);
  int*   off   = (int*)alloc(256);
  int*   cur   = (int*)alloc(256);
  size_t fixed_used = (size_t)(w - (uint8_t*)d_ws);

  // adaptive chunk rows: act1h (fp16) + act2 (fp16) = 8192 B/row, 256-row granules
  long long availLL = (long long)ws_size - (long long)fixed_used - 4096;
  int R = 0;
  if (availLL > 0) {
    long long r = availLL / (HID * 2 + HID * 2);
    if (r > PADTOT) r = PADTOT;
    R = (int)(r & ~255LL);
  }
  if (R < 256) {   // diagnostic fallback: out[0] = ws_size in MB
    hipMemsetAsync(d_out, 0, (size_t)out_size * sizeof(float), stream);
    probe_kernel<<<1, 64, 0, stream>>>(out, (float)(ws_size >> 20));
    return;
  }
  unsigned short* act1h = (unsigned short*)alloc((size_t)R * HID * 2);
  unsigned short* act2  = (unsigned short*)alloc((size_t)R * HID * 2);
  const bool single = (R >= PADTOT);   // Y (fp16 [PADTOT][1024]) aliases act1h
  unsigned short* Yh = act1h;

  hipMemsetAsync(cnt, 0, NEXP * sizeof(int), stream);
  hipMemsetAsync(rows, 0, (size_t)PADTOT * 4, stream);   // dummy rows -> token 0
  hipMemsetAsync(roww, 0, (size_t)PADTOT * 4, stream);   // dummy weight -> 0.0
  if (!single)
    hipMemsetAsync(d_out, 0, (size_t)out_size * sizeof(float), stream);  // atomic target

  wg1t_kernel<<<16, 256, 0, stream>>>(Wg1, Wg1t);
  gate_kernel<<<N_TOK / 8, 256, 0, stream>>>(x, Wg1t, Wg2, tok_e, tok_w);
  hist_kernel<<<2 * N_TOK / 512, 256, 0, stream>>>(tok_e, cnt);
  offsets_kernel<<<1, 64, 0, stream>>>(cnt, off, cur);
  scatter_kernel<<<N_TOK / 256, 256, 0, stream>>>(tok_e, tok_w, cur, rows, roww, pair);

  convert_x_kernel<<<(N_TOK * DIM / 8) / 256, 256, 0, stream>>>(x, xh);
  wconv_kernel<<<dim3(HID / 64, DIM / 64, NEXP), 256, 0, stream>>>(W1, Wt1, DIM, HID);
  wconv_kernel<<<dim3(HID / 64, HID / 64, NEXP), 256, 0, stream>>>(W2, Wt2, HID, HID);
  wconv_kernel<<<dim3(OUTD / 64, HID / 64, NEXP), 256, 0, stream>>>(W3, Wt3, HID, OUTD);

  for (int c0 = 0; c0 < PADTOT; c0 += R) {
    int Rc = PADTOT - c0; if (Rc > R) Rc = R;
    const int yt = Rc / 256;
    gemm256_kernel<0><<<8 * yt, 512, 0, stream>>>(xh, Wt1, act1h, nullptr, b1,
                                                  rows, roww, off, DIM, HID, DIM, c0, 3);
    ln_gelu_kernel<<<Rc / 4, 256, 0, stream>>>(act1h, act2, g1, be1, off, c0);
    gemm256_kernel<1><<<8 * yt, 512, 0, stream>>>(act2, Wt2, act1h, nullptr, b2,
                                                  rows, roww, off, HID, HID, HID, c0, 3);
    ln_gelu_kernel<<<Rc / 4, 256, 0, stream>>>(act1h, act2, g2, be2, off, c0);
    if (single)
      gemm256_kernel<3><<<4 * yt, 512, 0, stream>>>(act2, Wt3, Yh, nullptr, b3,
                                                    rows, roww, off, HID, OUTD, HID, c0, 2);
    else
      gemm256_kernel<2><<<4 * yt, 512, 0, stream>>>(act2, Wt3, nullptr, out, b3,
                                                    rows, roww, off, HID, OUTD, HID, c0, 2);
  }
  if (single)
    combine_kernel<<<N_TOK, 256, 0, stream>>>(Yh, pair, out);
}